// Round 13
// baseline (261.547 us; speedup 1.0000x reference)
//
#include <hip/hip_runtime.h>
#include <math.h>

#define UNITS 80
#define LATENT 128
#define IN_DIM 256
#define BATCH 8192
#define SEQ 256
#define G 320            // 4*UNITS
#define H2 160           // 2*UNITS
#define ROW_F4 (SEQ * UNITS / 4)             // 5120 f4 per batch row
#define TOT_F4 ((long long)BATCH * ROW_F4)   // 41,943,040 f4

#define TPB 640          // 10 waves
#define RPB 8            // rows per compute block
#define NBLK (BATCH / RPB)   // 1024 blocks

#define WB2 260          // body-writer blocks (~1.02/CU, fill-like concurrency)
#define WT2 256          // fill-like block size
#define WSTRIDE2 (WB2 * WT2)   // 66560 f4 = 13*5120 -> within-row offset const

typedef float f4 __attribute__((ext_vector_type(4)));

__device__ __forceinline__ float sigf(float v) {
    return 1.0f / (1.0f + __expf(-v));
}

// ---------------------------------------------------------------------------
// K1: R12's register-tiled fused compute, body stores removed.
//   per block (8 rows): in-block yc -> lat (2 rows/thr) -> gates (4 rows/thr)
//   -> outLSTM (4 rows/thr) -> store s=0 slices only. Block 0 publishes yc.
// ---------------------------------------------------------------------------
__global__ __launch_bounds__(TPB)
void compute_kernel(const float* __restrict__ x,
                    const float* __restrict__ Wl, const float* __restrict__ bl,
                    const float* __restrict__ Kf, const float* __restrict__ bf,
                    const float* __restrict__ Kb, const float* __restrict__ bb,
                    const float* __restrict__ K1, const float* __restrict__ b1,
                    float* __restrict__ yc, float* __restrict__ out) {
    __shared__ float z2[2 * G];
    __shared__ float h_c[H2];
    __shared__ float yc_s[UNITS];
    __shared__ float xs[RPB * IN_DIM];
    __shared__ float lat_s[RPB * LATENT];
    __shared__ float h_s[RPB * H2];
    __shared__ float y_s[RPB * UNITS];

    const int t = threadIdx.x;
    const int R0 = blockIdx.x * RPB;

    // x stage: 8 rows x 256 f32 = 512 f4
    if (t < RPB * IN_DIM / 4)
        ((f4*)xs)[t] = ((const f4*)(x + (size_t)R0 * IN_DIM))[t];

    // yc step A: z = colsum(K) + b (all-ones input), fw|bw halves in parallel
    {
        const float* K   = (t < G) ? Kf : Kb;
        const float* bia = (t < G) ? bf : bb;
        const int c = (t < G) ? t : t - G;
        float acc = bia[c];
#pragma unroll 8
        for (int l = 0; l < LATENT; ++l) acc += K[l * G + c];
        z2[t] = acc;
    }
    __syncthreads();

    // yc step B (f gate dead: c0=0; relu(c)=c since c>=0)
    if (t < UNITS) {
        h_c[t] = sigf(z2[240 + t]) * sigf(z2[t]) * fmaxf(z2[160 + t], 0.f);
    } else if (t >= G && t < G + UNITS) {
        const int u = t - G;
        h_c[UNITS + u] = sigf(z2[G + 240 + u]) * sigf(z2[G + u]) * fmaxf(z2[G + 160 + u], 0.f);
    }
    __syncthreads();

    // yc step C
    if (t < G) {
        float acc = b1[t];
#pragma unroll 8
        for (int l = 0; l < H2; ++l) acc = fmaf(h_c[l], K1[l * G + t], acc);
        z2[t] = acc;
    }
    __syncthreads();
    if (t < UNITS) yc_s[t] = sigf(z2[240 + t]) * sigf(z2[t]) * fmaxf(z2[160 + t], 0.f);

    // lat = x @ W_lat + b_lat : col = t&127, 2 rows per thread
    if (t < 512) {
        const int col = t & 127;
        const int rg  = t >> 7;
        float a0 = bl[col], a1 = a0;
        const float* xr0 = xs + (2 * rg) * IN_DIM;
        const float* xr1 = xr0 + IN_DIM;
#pragma unroll 4
        for (int l = 0; l < IN_DIM; ++l) {
            const float w = Wl[l * LATENT + col];
            a0 = fmaf(xr0[l], w, a0);
            a1 = fmaf(xr1[l], w, a1);
        }
        lat_s[(2 * rg) * LATENT + col] = a0;
        lat_s[(2 * rg + 1) * LATENT + col] = a1;
    }
    __syncthreads();

    // fw/bw gates: 4 rows per thread
    if (t < G) {
        const int u = t % UNITS;
        const int g = t / UNITS;
        const int half = g >> 1;
        const int r0 = (g & 1) * 4;
        const float* K   = half ? Kb : Kf;
        const float* bia = half ? bb : bf;
        float ai[4], ac[4], ao[4];
#pragma unroll
        for (int r = 0; r < 4; ++r) { ai[r] = bia[u]; ac[r] = bia[160 + u]; ao[r] = bia[240 + u]; }
#pragma unroll 2
        for (int k = 0; k < LATENT; ++k) {
            const float wi = K[k * G + u];
            const float wc = K[k * G + 160 + u];
            const float wo = K[k * G + 240 + u];
#pragma unroll
            for (int r = 0; r < 4; ++r) {
                const float lv = lat_s[(r0 + r) * LATENT + k];
                ai[r] = fmaf(lv, wi, ai[r]);
                ac[r] = fmaf(lv, wc, ac[r]);
                ao[r] = fmaf(lv, wo, ao[r]);
            }
        }
#pragma unroll
        for (int r = 0; r < 4; ++r)
            h_s[(r0 + r) * H2 + half * UNITS + u] =
                sigf(ao[r]) * sigf(ai[r]) * fmaxf(ac[r], 0.f);
    }
    __syncthreads();

    // output LSTM: 4 rows per thread
    if (t < 2 * UNITS) {
        const int u = t % UNITS;
        const int g = t / UNITS;
        const int r0 = g * 4;
        float ai[4], ac[4], ao[4];
#pragma unroll
        for (int r = 0; r < 4; ++r) { ai[r] = b1[u]; ac[r] = b1[160 + u]; ao[r] = b1[240 + u]; }
#pragma unroll 2
        for (int k = 0; k < H2; ++k) {
            const float wi = K1[k * G + u];
            const float wc = K1[k * G + 160 + u];
            const float wo = K1[k * G + 240 + u];
#pragma unroll
            for (int r = 0; r < 4; ++r) {
                const float hv = h_s[(r0 + r) * H2 + k];
                ai[r] = fmaf(hv, wi, ai[r]);
                ac[r] = fmaf(hv, wc, ac[r]);
                ao[r] = fmaf(hv, wo, ao[r]);
            }
        }
#pragma unroll
        for (int r = 0; r < 4; ++r)
            y_s[(r0 + r) * UNITS + u] = sigf(ao[r]) * sigf(ai[r]) * fmaxf(ac[r], 0.f);
    }
    __syncthreads();

    __builtin_amdgcn_sched_barrier(0);

    // s=0 slices only: 8 rows x 20 f4
    {
        const f4* ys4 = (const f4*)y_s;
        f4* out4 = (f4*)out;
        if (t < RPB * (UNITS / 4)) {
            const int row = t / (UNITS / 4);
            const int q = t - row * (UNITS / 4);
            __builtin_nontemporal_store(ys4[t], out4 + (size_t)(R0 + row) * ROW_F4 + q);
        }
        // block 0 publishes yc for K2
        if (blockIdx.x == 0 && t < UNITS) yc[t] = yc_s[t];
    }
}

// ---------------------------------------------------------------------------
// K2: fill-exact body writer. 260 blocks x 256 thr (~1 block/CU, ~4 waves/CU),
// plain f4 stores, whole-grid stride (multiple of ROW_F4 so the within-row
// offset — and hence the yc value — is constant per thread). Threads in the
// s=0 slice (c < 20) skip; holes are 5 aligned 64B lines, full-line coverage
// everywhere else (no RFO, per rocclr fill's FETCH~0).
// ---------------------------------------------------------------------------
__global__ __launch_bounds__(WT2)
void body_kernel(const float* __restrict__ yc, float* __restrict__ out) {
    const long long g0 = (long long)blockIdx.x * WT2 + threadIdx.x;
    const int c = (int)(g0 % ROW_F4);          // constant across iterations
    if (c < UNITS / 4) return;
    const f4 yv = ((const f4*)yc)[c % (UNITS / 4)];
    f4* out4 = (f4*)out;
    for (long long g = g0; g < TOT_F4; g += WSTRIDE2)
        out4[g] = yv;
}

extern "C" void kernel_launch(void* const* d_in, const int* in_sizes, int n_in,
                              void* d_out, int out_size, void* d_ws, size_t ws_size,
                              hipStream_t stream) {
    const float* x   = (const float*)d_in[0];
    // d_in[1] = size (scalar, fixed 256)
    const float* Wl  = (const float*)d_in[2];
    const float* bl  = (const float*)d_in[3];
    const float* Kf  = (const float*)d_in[4];
    const float* bf  = (const float*)d_in[5];
    const float* Kb  = (const float*)d_in[6];
    const float* bb  = (const float*)d_in[7];
    const float* K1  = (const float*)d_in[8];
    const float* b1  = (const float*)d_in[9];
    float* out = (float*)d_out;
    float* yc  = (float*)d_ws;   // 80 floats

    compute_kernel<<<NBLK, TPB, 0, stream>>>(x, Wl, bl, Kf, bf, Kb, bb, K1, b1, yc, out);
    body_kernel<<<WB2, WT2, 0, stream>>>(yc, out);
}

// Round 15
// 184.463 us; speedup vs baseline: 1.4179x; 1.4179x over previous
//
#include <hip/hip_runtime.h>
#include <math.h>

#define UNITS 80
#define LATENT 128
#define IN_DIM 256
#define BATCH 8192
#define SEQ 256
#define G 320            // 4*UNITS
#define H2 160           // 2*UNITS
#define ROW_F4 (SEQ * UNITS / 4)   // 5120 f4 per batch row

#define TPB 640          // 10 waves; 640 % 20 == 0 (yc f4 period)
#define RPB 8            // rows per block
#define NBLK (BATCH / RPB)   // 1024 blocks

typedef float f4 __attribute__((ext_vector_type(4)));

__device__ __forceinline__ float sigf(float v) {
    return 1.0f / (1.0f + __expf(-v));
}

// ---------------------------------------------------------------------------
// Single fused kernel (best-known: R12, 184.79 us). Per block (8 rows):
//   0) in-block yc = decode_step(ones)  (identical in every block; warms L2)
//   1) x stage -> lat (2 rows/thr) -> gates (4 rows/thr) -> outLSTM (4 rows/thr)
//   2) store phase: pure nt f4 stream, s=0 slice folded into k=0 iteration.
// Write stream saturates the d_out write path (~3.63 TB/s); compute is fully
// hidden (R6 vs R12: 3x L2-traffic difference, identical dur).
// ---------------------------------------------------------------------------
__global__ __launch_bounds__(TPB)
void main_kernel(const float* __restrict__ x,
                 const float* __restrict__ Wl, const float* __restrict__ bl,
                 const float* __restrict__ Kf, const float* __restrict__ bf,
                 const float* __restrict__ Kb, const float* __restrict__ bb,
                 const float* __restrict__ K1, const float* __restrict__ b1,
                 float* __restrict__ out) {
    __shared__ float z2[2 * G];           // yc gate pre-activations
    __shared__ float h_c[H2];             // yc hidden
    __shared__ float yc_s[UNITS];
    __shared__ float xs[RPB * IN_DIM];
    __shared__ float lat_s[RPB * LATENT];
    __shared__ float h_s[RPB * H2];
    __shared__ float y_s[RPB * UNITS];

    const int t = threadIdx.x;
    const int R0 = blockIdx.x * RPB;

    // ---- x stage: 8 rows x 256 f32 = 512 f4 ----
    if (t < RPB * IN_DIM / 4)
        ((f4*)xs)[t] = ((const f4*)(x + (size_t)R0 * IN_DIM))[t];

    // ---- yc step A: z = colsum(K) + b (all-ones input), fw|bw in parallel ----
    {
        const float* K   = (t < G) ? Kf : Kb;
        const float* bia = (t < G) ? bf : bb;
        const int c = (t < G) ? t : t - G;
        float acc = bia[c];
#pragma unroll 8
        for (int l = 0; l < LATENT; ++l) acc += K[l * G + c];
        z2[t] = acc;
    }
    __syncthreads();

    // ---- yc step B: h (f gate dead: c0=0; relu(c)=c since c>=0) ----
    if (t < UNITS) {
        h_c[t] = sigf(z2[240 + t]) * sigf(z2[t]) * fmaxf(z2[160 + t], 0.f);
    } else if (t >= G && t < G + UNITS) {
        const int u = t - G;
        h_c[UNITS + u] = sigf(z2[G + 240 + u]) * sigf(z2[G + u]) * fmaxf(z2[G + 160 + u], 0.f);
    }
    __syncthreads();

    // ---- yc step C: z1 = h @ K1 + b1; yc_s = gate(z1) ----
    if (t < G) {
        float acc = b1[t];
#pragma unroll 8
        for (int l = 0; l < H2; ++l) acc = fmaf(h_c[l], K1[l * G + t], acc);
        z2[t] = acc;   // reuse z2[0..319]
    }
    __syncthreads();
    if (t < UNITS) yc_s[t] = sigf(z2[240 + t]) * sigf(z2[t]) * fmaxf(z2[160 + t], 0.f);
    __syncthreads();

    // ---- lat = x @ W_lat + b_lat : col = t&127, 2 rows per thread ----
    if (t < 512) {
        const int col = t & 127;
        const int rg  = t >> 7;            // 0..3 -> rows {2rg, 2rg+1}
        float a0 = bl[col], a1 = a0;
        const float* xr0 = xs + (2 * rg) * IN_DIM;
        const float* xr1 = xr0 + IN_DIM;
#pragma unroll 4
        for (int l = 0; l < IN_DIM; ++l) {
            const float w = Wl[l * LATENT + col];
            a0 = fmaf(xr0[l], w, a0);
            a1 = fmaf(xr1[l], w, a1);
        }
        lat_s[(2 * rg) * LATENT + col] = a0;
        lat_s[(2 * rg + 1) * LATENT + col] = a1;
    }
    __syncthreads();

    // ---- fw/bw gates: u=t%80, g=t/80: half=g>>1, rows (g&1)*4 .. +3 ----
    if (t < G) {
        const int u = t % UNITS;
        const int g = t / UNITS;           // 0..3
        const int half = g >> 1;           // 0=fw, 1=bw
        const int r0 = (g & 1) * 4;
        const float* K   = half ? Kb : Kf;
        const float* bia = half ? bb : bf;
        float ai[4], ac[4], ao[4];
#pragma unroll
        for (int r = 0; r < 4; ++r) { ai[r] = bia[u]; ac[r] = bia[160 + u]; ao[r] = bia[240 + u]; }
#pragma unroll 2
        for (int k = 0; k < LATENT; ++k) {
            const float wi = K[k * G + u];
            const float wc = K[k * G + 160 + u];
            const float wo = K[k * G + 240 + u];
#pragma unroll
            for (int r = 0; r < 4; ++r) {
                const float lv = lat_s[(r0 + r) * LATENT + k];
                ai[r] = fmaf(lv, wi, ai[r]);
                ac[r] = fmaf(lv, wc, ac[r]);
                ao[r] = fmaf(lv, wo, ao[r]);
            }
        }
#pragma unroll
        for (int r = 0; r < 4; ++r)
            h_s[(r0 + r) * H2 + half * UNITS + u] =
                sigf(ao[r]) * sigf(ai[r]) * fmaxf(ac[r], 0.f);
    }
    __syncthreads();

    // ---- output LSTM: u=t%80, g=t/80: rows g*4 .. g*4+3 ----
    if (t < 2 * UNITS) {
        const int u = t % UNITS;
        const int g = t / UNITS;           // 0..1
        const int r0 = g * 4;
        float ai[4], ac[4], ao[4];
#pragma unroll
        for (int r = 0; r < 4; ++r) { ai[r] = b1[u]; ac[r] = b1[160 + u]; ao[r] = b1[240 + u]; }
#pragma unroll 2
        for (int k = 0; k < H2; ++k) {
            const float wi = K1[k * G + u];
            const float wc = K1[k * G + 160 + u];
            const float wo = K1[k * G + 240 + u];
#pragma unroll
            for (int r = 0; r < 4; ++r) {
                const float hv = h_s[(r0 + r) * H2 + k];
                ai[r] = fmaf(hv, wi, ai[r]);
                ac[r] = fmaf(hv, wc, ac[r]);
                ao[r] = fmaf(hv, wo, ao[r]);
            }
        }
#pragma unroll
        for (int r = 0; r < 4; ++r)
            y_s[(r0 + r) * UNITS + u] = sigf(ao[r]) * sigf(ai[r]) * fmaxf(ac[r], 0.f);
    }
    __syncthreads();

    // keep stores strictly after all load-uses (no vmcnt interlock)
    __builtin_amdgcn_sched_barrier(0);

    // ---- store phase: 8 rows x 5120 f4, s=0 folded into k=0 ----
    {
        const f4 yv = ((const f4*)yc_s)[t % (UNITS / 4)];   // const per thread
        const f4* ys4 = (const f4*)y_s;                     // [8][20] f4
        f4* out4 = (f4*)out;
#pragma unroll
        for (int r = 0; r < RPB; ++r) {
            f4* rowp = out4 + (size_t)(R0 + r) * ROW_F4;
            const f4 v0 = (t < UNITS / 4) ? ys4[r * (UNITS / 4) + t] : yv;
            __builtin_nontemporal_store(v0, rowp + t);
#pragma unroll
            for (int k = 1; k < ROW_F4 / TPB; ++k)          // k = 1..7
                __builtin_nontemporal_store(yv, rowp + t + k * TPB);
        }
    }
}

extern "C" void kernel_launch(void* const* d_in, const int* in_sizes, int n_in,
                              void* d_out, int out_size, void* d_ws, size_t ws_size,
                              hipStream_t stream) {
    const float* x   = (const float*)d_in[0];
    // d_in[1] = size (scalar, fixed 256)
    const float* Wl  = (const float*)d_in[2];
    const float* bl  = (const float*)d_in[3];
    const float* Kf  = (const float*)d_in[4];
    const float* bf  = (const float*)d_in[5];
    const float* Kb  = (const float*)d_in[6];
    const float* bb  = (const float*)d_in[7];
    const float* K1  = (const float*)d_in[8];
    const float* b1  = (const float*)d_in[9];
    float* out = (float*)d_out;

    main_kernel<<<NBLK, TPB, 0, stream>>>(x, Wl, bl, Kf, bf, Kb, bb, K1, b1, out);
}